// Round 6
// baseline (1176.955 us; speedup 1.0000x reference)
//
#include <hip/hip_runtime.h>
#include <hip/hip_bf16.h>
#include <math.h>

#define B_   8192
#define F_   48
#define T_   512
#define L_   8
#define NBLK 256
#define THR  1024
#define NW   16          // waves per block
#define RPB  32          // rows per block
#define HST  520         // H LDS row stride in shorts (1040B; 65 uint4)
#define ZS   52          // z LDS row stride in floats

typedef unsigned short ushort_t;
typedef unsigned int   uint_t;
typedef __attribute__((ext_vector_type(8))) short short8;
typedef __attribute__((ext_vector_type(4))) float f32x4;

#define MFMA(a,b,c) __builtin_amdgcn_mfma_f32_16x16x32_bf16(a,b,c,0,0,0)

__device__ inline ushort_t f2bf(float x) {
    __hip_bfloat16 h = __float2bfloat16(x);
    return *reinterpret_cast<ushort_t*>(&h);
}
__device__ inline float bf2f(ushort_t x) {
    __hip_bfloat16 h;
    *reinterpret_cast<ushort_t*>(&h) = x;
    return __bfloat162float(h);
}
__device__ inline short8 negbf(short8 v) {
    short8 r;
    #pragma unroll
    for (int i = 0; i < 8; ++i) r[i] = v[i] ^ (short)0x8000;
    return r;
}
__device__ inline short8 pack8(float4 a, float4 b) {
    short8 r;
    r[0]=(short)f2bf(a.x); r[1]=(short)f2bf(a.y); r[2]=(short)f2bf(a.z); r[3]=(short)f2bf(a.w);
    r[4]=(short)f2bf(b.x); r[5]=(short)f2bf(b.y); r[6]=(short)f2bf(b.z); r[7]=(short)f2bf(b.w);
    return r;
}

// block-wide sum: wave butterfly + 16-slot LDS combine (2 syncthreads)
__device__ inline float blk_sum(float v, float* red16) {
    #pragma unroll
    for (int s = 32; s > 0; s >>= 1) v += __shfl_xor(v, s, 64);
    __syncthreads();                       // protect previous red16 use
    if ((threadIdx.x & 63) == 0) red16[threadIdx.x >> 6] = v;
    __syncthreads();
    float t = 0.f;
    #pragma unroll
    for (int w = 0; w < NW; ++w) t += red16[w];
    return t;
}

// sharded barrier: 8 counters on separate 128B lines
__device__ inline void bar_add(uint_t* cnt, int blk) {
    __hip_atomic_fetch_add(&cnt[(blk & 7) * 32], 1u, __ATOMIC_RELEASE, __HIP_MEMORY_SCOPE_AGENT);
}
__device__ inline void bar_wait(uint_t* cnt, uint_t tgt) {
    if (threadIdx.x == 0) {
        for (;;) {
            uint_t s = 0;
            #pragma unroll
            for (int i = 0; i < 8; ++i)
                s += __hip_atomic_load(&cnt[i * 32], __ATOMIC_RELAXED, __HIP_MEMORY_SCOPE_AGENT);
            if (s >= tgt) break;
            __builtin_amdgcn_s_sleep(2);
        }
    }
    __threadfence();
    __syncthreads();
}
__device__ inline float aload(const float* p) {
    return __hip_atomic_load(p, __ATOMIC_RELAXED, __HIP_MEMORY_SCOPE_AGENT);
}
__device__ inline void astore(float* p, float v) {
    __hip_atomic_store(p, v, __ATOMIC_RELAXED, __HIP_MEMORY_SCOPE_AGENT);
}

// soft-threshold on a packed bf16 pair
__device__ inline uint_t act2(uint_t v, float lam, float th1, float& cnt_) {
    float lo = __uint_as_float(v << 16);
    float hi = __uint_as_float(v & 0xffff0000u);
    float ml = fabsf(lo), mh = fabsf(hi);
    float fl = th1 * copysignf(fmaxf(ml - lam, 0.f), lo);
    float fh = th1 * copysignf(fmaxf(mh - lam, 0.f), hi);
    cnt_ += ((ml > lam) ? 1.f : 0.f) + ((mh > lam) ? 1.f : 0.f);
    return ((uint_t)f2bf(fl)) | (((uint_t)f2bf(fh)) << 16);
}

// ---------- prep: frag-linear bf16 layouts + zero barrier shards ----------
// Af: [L][tile32][k2(2)][quad4][m16][8]  (fwd B-frags; wave reads 1KiB contiguous)
// At: [L][ft3][ks16][quad4][m16][8]      (bwd B-frags)
// Df: [ft3][ks16][quad4][m16][8]         (final B-frags)
__global__ __launch_bounds__(256) void k_pre(
    const float* __restrict__ Ar, const float* __restrict__ Ai,
    const float* __restrict__ Dr, const float* __restrict__ Di,
    ushort_t* __restrict__ Afr, ushort_t* __restrict__ Afi,
    ushort_t* __restrict__ Atr, ushort_t* __restrict__ Ati,
    ushort_t* __restrict__ Dfr, ushort_t* __restrict__ Dfi,
    uint_t* __restrict__ cnt)
{
    const int gt = blockIdx.x * 256 + threadIdx.x;
    const int gs = gridDim.x * 256;
    if (gt < 256) cnt[gt] = 0u;
    for (int idx = gt; idx < L_ * 32768; idx += gs) {
        int j = idx & 7, rest = idx >> 3;
        int mm = rest & 15; rest >>= 4;
        int qq = rest & 3;  rest >>= 2;
        int k2 = rest & 1;  rest >>= 1;
        int tile = rest & 31;
        int l = rest >> 5;
        int t = tile * 16 + mm, k = k2 * 32 + qq * 8 + j;
        float vr = 0.f, vi = 0.f;
        if (k < 48) { int g = l * 24576 + t * 48 + k; vr = Ar[g]; vi = Ai[g]; }
        Afr[idx] = f2bf(vr); Afi[idx] = f2bf(vi);
    }
    for (int idx = gt; idx < L_ * 24576; idx += gs) {
        int j = idx & 7, rest = idx >> 3;
        int mm = rest & 15; rest >>= 4;
        int qq = rest & 3;  rest >>= 2;
        int ks = rest & 15; rest >>= 4;
        int ft = rest % 3;
        int l = rest / 3;
        int f = ft * 16 + mm, k = ks * 32 + qq * 8 + j;
        int g = l * 24576 + k * 48 + f;
        Atr[idx] = f2bf(Ar[g]); Ati[idx] = f2bf(Ai[g]);
    }
    for (int idx = gt; idx < 24576; idx += gs) {
        int j = idx & 7, rest = idx >> 3;
        int mm = rest & 15; rest >>= 4;
        int qq = rest & 3;  rest >>= 2;
        int ks = rest & 15;
        int ft = rest >> 4;
        int f = ft * 16 + mm, k = ks * 32 + qq * 8 + j;
        Dfr[idx] = f2bf(Dr[k * 48 + f]); Dfi[idx] = f2bf(Di[k * 48 + f]);
    }
}

// ---------- persistent cooperative kernel ----------
// 256 blocks x 1024 threads; block owns rows [blk*32,+32); z fp32 + H bf16 in LDS.
__global__ __launch_bounds__(THR, 1) void k_lamp(
    const float* __restrict__ u,
    const ushort_t* __restrict__ Afr, const ushort_t* __restrict__ Afi,
    const ushort_t* __restrict__ Atr, const ushort_t* __restrict__ Ati,
    const ushort_t* __restrict__ Dfr, const ushort_t* __restrict__ Dfi,
    const float* __restrict__ th,
    float* part_sig, float* part_r, float* part_i, uint_t* cnt,
    float* __restrict__ out)
{
    extern __shared__ char dyn[];
    float*    pR   = (float*)dyn;                  // [8][3][16][17] 26112 B
    float*    pI   = pR + 8 * 3 * 16 * 17;         // 26112 B
    float*    zreL = pI + 8 * 3 * 16 * 17;         // 6656 B
    float*    zimL = zreL + RPB * ZS;              // 6656 B
    float*    red16= zimL + RPB * ZS;              // 64 B
    ushort_t* HreL = (ushort_t*)(red16 + 16);      // 33280 B
    ushort_t* HimL = HreL + RPB * HST;             // 33280 B  => 132160 B

    const int tid = threadIdx.x, blk = blockIdx.x;
    const int row0 = blk * RPB;
    const int wave = tid >> 6, lane = tid & 63;
    const int quad = lane >> 4, m = lane & 15;
    const int rows16 = (wave >> 3) * 16;           // fwd/bwd: row-tile (0 or 16)
    const int cgrp = wave & 7;                     // fwd: column eighth (4 tiles)
    const int rt = wave >> 3, kq = wave & 7;       // bwd: row-tile / K-eighth
    const float2* u2 = (const float2*)u;
    uint_t tgt = 0;

    // prologue: u -> z LDS, sigma partial
    float acc = 0.f;
    #pragma unroll
    for (int k2 = 0; k2 < 2; ++k2) {
        int j = tid + k2 * THR;
        if (j < RPB * F_) {
            int r = j / 48, c = j - r * 48;
            float2 v = u2[(row0 + r) * 48 + c];
            zreL[r * ZS + c] = v.x; zimL[r * ZS + c] = v.y;
            acc += v.x * v.x + v.y * v.y;
        }
    }
    float s0 = blk_sum(acc, red16);
    if (tid == 0) { astore(&part_sig[blk], s0); bar_add(cnt, blk); }
    tgt += NBLK;

    for (int l = 0; l < L_; ++l) {
        // z A-frags from LDS fp32 (K=48 padded to 64)
        const float* zpr = zreL + (rows16 + m) * ZS;
        const float* zpi = zimL + (rows16 + m) * ZS;
        short8 zr0 = pack8(*(const float4*)(zpr + quad * 8), *(const float4*)(zpr + quad * 8 + 4));
        short8 zi0 = pack8(*(const float4*)(zpi + quad * 8), *(const float4*)(zpi + quad * 8 + 4));
        short8 zr1 = {0,0,0,0,0,0,0,0}, zi1 = {0,0,0,0,0,0,0,0};
        if (quad < 2) {
            zr1 = pack8(*(const float4*)(zpr + 32 + quad * 8), *(const float4*)(zpr + 36 + quad * 8));
            zi1 = pack8(*(const float4*)(zpi + 32 + quad * 8), *(const float4*)(zpi + 36 + quad * 8));
        }
        short8 zin0 = negbf(zi0), zin1 = negbf(zi1);

        // forward GEMM; store R = Hold + Z to H LDS (activation deferred past barrier)
        const ushort_t* Aflr = Afr + (size_t)l * 32768;
        const ushort_t* Afli = Afi + (size_t)l * 32768;
        #pragma unroll
        for (int ct = 0; ct < 4; ++ct) {
            const int tile = cgrp * 4 + ct;
            const ushort_t* rp = Aflr + (size_t)(tile * 2) * 512 + lane * 8;
            const ushort_t* ip = Afli + (size_t)(tile * 2) * 512 + lane * 8;
            short8 ar0 = *(const short8*)rp;
            short8 ar1 = *(const short8*)(rp + 512);
            short8 ai0 = *(const short8*)ip;
            short8 ai1 = *(const short8*)(ip + 512);
            f32x4 accR = {0.f,0.f,0.f,0.f}, accI = {0.f,0.f,0.f,0.f};
            accR = MFMA(zr0, ar0, accR);
            accR = MFMA(zr1, ar1, accR);
            accR = MFMA(zin0, ai0, accR);
            accR = MFMA(zin1, ai1, accR);
            accI = MFMA(zr0, ai0, accI);
            accI = MFMA(zr1, ai1, accI);
            accI = MFMA(zi0, ar0, accI);
            accI = MFMA(zi1, ar1, accI);
            const int t = tile * 16 + m;
            #pragma unroll
            for (int reg = 0; reg < 4; ++reg) {
                const int lr = rows16 + quad * 4 + reg;
                float Rr = accR[reg], Ri = accI[reg];
                if (l > 0) { Rr += bf2f(HreL[lr * HST + t]); Ri += bf2f(HimL[lr * HST + t]); }
                HreL[lr * HST + t] = f2bf(Rr);
                HimL[lr * HST + t] = f2bf(Ri);
            }
        }

        // sigma barrier (hidden behind the GEMM above) + lambda
        bar_wait(cnt, tgt);
        float ssum = blk_sum((tid < NBLK) ? aload(&part_sig[tid]) : 0.f, red16);
        const float lam = th[l * 3] * sqrtf(ssum * (1.0f / 48.0f));
        const float th1 = th[l * 3 + 1];

        // vectorized activation pass over H LDS (R -> Hn), count partials
        float cr = 0.f, ci = 0.f;
        uint4* Hr4 = (uint4*)HreL;
        uint4* Hi4 = (uint4*)HimL;
        #pragma unroll
        for (int k2 = 0; k2 < 2; ++k2) {
            int j = tid + k2 * THR;          // 0..2047
            int r = j >> 6, c4 = j & 63;     // 64 uint4 of data per row (65 incl pad)
            uint4* pr = Hr4 + r * 65 + c4;
            uint4* pi = Hi4 + r * 65 + c4;
            uint4 xr = *pr, xi = *pi;
            xr.x = act2(xr.x, lam, th1, cr); xr.y = act2(xr.y, lam, th1, cr);
            xr.z = act2(xr.z, lam, th1, cr); xr.w = act2(xr.w, lam, th1, cr);
            xi.x = act2(xi.x, lam, th1, ci); xi.y = act2(xi.y, lam, th1, ci);
            xi.z = act2(xi.z, lam, th1, ci); xi.w = act2(xi.w, lam, th1, ci);
            *pr = xr; *pi = xi;
        }

        if (l == L_ - 1) { __syncthreads(); break; }

        float csr = blk_sum(cr, red16);      // also publishes Hn block-wide
        if (tid == 0) astore(&part_r[blk], csr);
        float csi = blk_sum(ci, red16);
        if (tid == 0) { astore(&part_i[blk], csi); bar_add(cnt, blk); }
        tgt += NBLK;

        // backward GEMM: h = Hn @ A; wave (rt,kq) does rows rt*16..+16, K-eighth kq
        const ushort_t* Atlr = Atr + (size_t)l * 24576;
        const ushort_t* Atli = Ati + (size_t)l * 24576;
        f32x4 aR[3], aI[3];
        #pragma unroll
        for (int q = 0; q < 3; ++q) { aR[q] = (f32x4){0,0,0,0}; aI[q] = (f32x4){0,0,0,0}; }
        #pragma unroll
        for (int ks = 0; ks < 2; ++ks) {
            const int ksa = kq * 2 + ks;
            const int k0 = ksa * 32 + quad * 8;
            short8 hr = *(const short8*)&HreL[(rt * 16 + m) * HST + k0];
            short8 hi = *(const short8*)&HimL[(rt * 16 + m) * HST + k0];
            short8 hin = negbf(hi);
            #pragma unroll
            for (int ft = 0; ft < 3; ++ft) {
                short8 br = *(const short8*)(Atlr + (size_t)((ft * 16 + ksa) * 64 + lane) * 8);
                short8 bi = *(const short8*)(Atli + (size_t)((ft * 16 + ksa) * 64 + lane) * 8);
                aR[ft] = MFMA(hr, br, aR[ft]);
                aR[ft] = MFMA(hin, bi, aR[ft]);
                aI[ft] = MFMA(hr, bi, aI[ft]);
                aI[ft] = MFMA(hi, br, aI[ft]);
            }
        }
        // two-phase K-partial combine: slot s = rt*4 + (kq&3); kq<4 store, kq>=4 add
        {
            const int s = rt * 4 + (kq & 3);
            if (kq < 4) {
                #pragma unroll
                for (int ft = 0; ft < 3; ++ft)
                    #pragma unroll
                    for (int reg = 0; reg < 4; ++reg) {
                        pR[((s * 3 + ft) * 16 + quad * 4 + reg) * 17 + m] = aR[ft][reg];
                        pI[((s * 3 + ft) * 16 + quad * 4 + reg) * 17 + m] = aI[ft][reg];
                    }
            }
            __syncthreads();
            if (kq >= 4) {
                #pragma unroll
                for (int ft = 0; ft < 3; ++ft)
                    #pragma unroll
                    for (int reg = 0; reg < 4; ++reg) {
                        pR[((s * 3 + ft) * 16 + quad * 4 + reg) * 17 + m] += aR[ft][reg];
                        pI[((s * 3 + ft) * 16 + quad * 4 + reg) * 17 + m] += aI[ft][reg];
                    }
            }
        }

        // b barrier (hidden behind backward GEMM); its syncthreads publishes pR/pI
        bar_wait(cnt, tgt);
        float bsr = blk_sum((tid < NBLK) ? aload(&part_r[tid]) : 0.f, red16);
        float bsi = blk_sum((tid < NBLK) ? aload(&part_i[tid]) : 0.f, red16);
        const float bre = th1 * bsr * (1.0f / 48.0f);
        const float bim = th1 * bsi * (1.0f / 48.0f);

        // z update + sigma partial
        float nrm = 0.f;
        #pragma unroll
        for (int k2 = 0; k2 < 2; ++k2) {
            int j = tid + k2 * THR;
            if (j < RPB * F_) {
                int r = j / 48, f = j - r * 48;
                int rt2 = r >> 4, lr = r & 15, ft = f >> 4, c = f & 15;
                float hR = 0.f, hI = 0.f;
                #pragma unroll
                for (int q = 0; q < 4; ++q) {
                    hR += pR[(((rt2 * 4 + q) * 3 + ft) * 16 + lr) * 17 + c];
                    hI += pI[(((rt2 * 4 + q) * 3 + ft) * 16 + lr) * 17 + c];
                }
                float2 uv = u2[(row0 + r) * 48 + f];
                float zr = zreL[r * ZS + f], zi = zimL[r * ZS + f];
                float znr = uv.x - hR + bre * zr;
                float zni = uv.y - hI + bim * zi;
                zreL[r * ZS + f] = znr; zimL[r * ZS + f] = zni;
                nrm += znr * znr + zni * zni;
            }
        }
        float ns = blk_sum(nrm, red16);
        if (tid == 0) { astore(&part_sig[blk], ns); bar_add(cnt, blk); }
        tgt += NBLK;
    }

    // final: out = Hn(LDS) @ DFT  (wave (rt,kq), K-split 8-way, two-phase combine)
    f32x4 fR[3], fI[3];
    #pragma unroll
    for (int q = 0; q < 3; ++q) { fR[q] = (f32x4){0,0,0,0}; fI[q] = (f32x4){0,0,0,0}; }
    #pragma unroll
    for (int ks = 0; ks < 2; ++ks) {
        const int ksa = kq * 2 + ks;
        const int k0 = ksa * 32 + quad * 8;
        short8 hr = *(const short8*)&HreL[(rt * 16 + m) * HST + k0];
        short8 hi = *(const short8*)&HimL[(rt * 16 + m) * HST + k0];
        short8 hin = negbf(hi);
        #pragma unroll
        for (int ft = 0; ft < 3; ++ft) {
            short8 br = *(const short8*)(Dfr + (size_t)((ft * 16 + ksa) * 64 + lane) * 8);
            short8 bi = *(const short8*)(Dfi + (size_t)((ft * 16 + ksa) * 64 + lane) * 8);
            fR[ft] = MFMA(hr, br, fR[ft]);
            fR[ft] = MFMA(hin, bi, fR[ft]);
            fI[ft] = MFMA(hr, bi, fI[ft]);
            fI[ft] = MFMA(hi, br, fI[ft]);
        }
    }
    {
        const int s = rt * 4 + (kq & 3);
        if (kq < 4) {
            #pragma unroll
            for (int ft = 0; ft < 3; ++ft)
                #pragma unroll
                for (int reg = 0; reg < 4; ++reg) {
                    pR[((s * 3 + ft) * 16 + quad * 4 + reg) * 17 + m] = fR[ft][reg];
                    pI[((s * 3 + ft) * 16 + quad * 4 + reg) * 17 + m] = fI[ft][reg];
                }
        }
        __syncthreads();
        if (kq >= 4) {
            #pragma unroll
            for (int ft = 0; ft < 3; ++ft)
                #pragma unroll
                for (int reg = 0; reg < 4; ++reg) {
                    pR[((s * 3 + ft) * 16 + quad * 4 + reg) * 17 + m] += fR[ft][reg];
                    pI[((s * 3 + ft) * 16 + quad * 4 + reg) * 17 + m] += fI[ft][reg];
                }
        }
    }
    __syncthreads();
    float2* out2 = (float2*)out;
    #pragma unroll
    for (int k2 = 0; k2 < 2; ++k2) {
        int j = tid + k2 * THR;
        if (j < RPB * F_) {
            int r = j / 48, f = j - r * 48;
            int rt2 = r >> 4, lr = r & 15, ft = f >> 4, c = f & 15;
            float hR = 0.f, hI = 0.f;
            #pragma unroll
            for (int q = 0; q < 4; ++q) {
                hR += pR[(((rt2 * 4 + q) * 3 + ft) * 16 + lr) * 17 + c];
                hI += pI[(((rt2 * 4 + q) * 3 + ft) * 16 + lr) * 17 + c];
            }
            out2[(row0 + r) * 48 + f] = make_float2(hR, hI);
        }
    }
}

extern "C" void kernel_launch(void* const* d_in, const int* in_sizes, int n_in,
                              void* d_out, int out_size, void* d_ws, size_t ws_size,
                              hipStream_t stream) {
    (void)in_sizes; (void)n_in; (void)out_size; (void)ws_size;
    const float* u  = (const float*)d_in[0];
    const float* Ar = (const float*)d_in[1];
    const float* Ai = (const float*)d_in[2];
    const float* th = (const float*)d_in[3];
    const float* Dr = (const float*)d_in[4];
    const float* Di = (const float*)d_in[5];
    float* out = (float*)d_out;

    char* p = (char*)d_ws;
    auto alloc = [&](size_t bytes) -> char* {
        char* r = p;
        p += (bytes + 255) & ~(size_t)255;
        return r;
    };
    float*    part_sig = (float*)alloc(NBLK * 4);
    float*    part_r   = (float*)alloc(NBLK * 4);
    float*    part_i   = (float*)alloc(NBLK * 4);
    uint_t*   cnt      = (uint_t*)alloc(256 * 4);   // 8 shards on 128B lines
    ushort_t* Afr = (ushort_t*)alloc((size_t)L_ * 32768 * 2);
    ushort_t* Afi = (ushort_t*)alloc((size_t)L_ * 32768 * 2);
    ushort_t* Atr = (ushort_t*)alloc((size_t)L_ * 24576 * 2);
    ushort_t* Ati = (ushort_t*)alloc((size_t)L_ * 24576 * 2);
    ushort_t* Dfr = (ushort_t*)alloc((size_t)24576 * 2);
    ushort_t* Dfi = (ushort_t*)alloc((size_t)24576 * 2);

    k_pre<<<256, 256, 0, stream>>>(Ar, Ai, Dr, Di, Afr, Afi, Atr, Ati, Dfr, Dfi, cnt);

    const uint_t lds_bytes = 132160;
    hipFuncSetAttribute((const void*)k_lamp,
                        hipFuncAttributeMaxDynamicSharedMemorySize, (int)lds_bytes);
    void* args[] = { (void*)&u, (void*)&Afr, (void*)&Afi, (void*)&Atr, (void*)&Ati,
                     (void*)&Dfr, (void*)&Dfi, (void*)&th,
                     (void*)&part_sig, (void*)&part_r, (void*)&part_i,
                     (void*)&cnt, (void*)&out };
    hipLaunchCooperativeKernel((void*)k_lamp, dim3(NBLK), dim3(THR), args,
                               lds_bytes, stream);
}

// Round 7
// 309.455 us; speedup vs baseline: 3.8033x; 3.8033x over previous
//
#include <hip/hip_runtime.h>
#include <hip/hip_bf16.h>
#include <math.h>

#define B_   8192
#define F_   48
#define T_   512
#define L_   8
#define NBLK 512
#define THR  512
#define NW   8           // waves per block
#define RPB  16          // rows per block
#define HST  520         // H LDS row stride in shorts (1040B; 65 uint4)
#define ZS   52          // z LDS row stride in floats

typedef unsigned short ushort_t;
typedef unsigned int   uint_t;
typedef __attribute__((ext_vector_type(8))) short short8;
typedef __attribute__((ext_vector_type(4))) float f32x4;

#define MFMA(a,b,c) __builtin_amdgcn_mfma_f32_16x16x32_bf16(a,b,c,0,0,0)

__device__ inline ushort_t f2bf(float x) {
    __hip_bfloat16 h = __float2bfloat16(x);
    return *reinterpret_cast<ushort_t*>(&h);
}
__device__ inline float bf2f(ushort_t x) {
    __hip_bfloat16 h;
    *reinterpret_cast<ushort_t*>(&h) = x;
    return __bfloat162float(h);
}
__device__ inline short8 negbf(short8 v) {
    short8 r;
    #pragma unroll
    for (int i = 0; i < 8; ++i) r[i] = v[i] ^ (short)0x8000;
    return r;
}
__device__ inline short8 pack8(float4 a, float4 b) {
    short8 r;
    r[0]=(short)f2bf(a.x); r[1]=(short)f2bf(a.y); r[2]=(short)f2bf(a.z); r[3]=(short)f2bf(a.w);
    r[4]=(short)f2bf(b.x); r[5]=(short)f2bf(b.y); r[6]=(short)f2bf(b.z); r[7]=(short)f2bf(b.w);
    return r;
}

// block-wide sum: wave butterfly + 8-slot LDS combine (2 syncthreads)
__device__ inline float blk_sum(float v, float* red8) {
    #pragma unroll
    for (int s = 32; s > 0; s >>= 1) v += __shfl_xor(v, s, 64);
    __syncthreads();                       // protect previous red8 use
    if ((threadIdx.x & 63) == 0) red8[threadIdx.x >> 6] = v;
    __syncthreads();
    float t = 0.f;
    #pragma unroll
    for (int w = 0; w < NW; ++w) t += red8[w];
    return t;
}

// sharded barrier: 16 counters on separate 128B lines
__device__ inline void bar_add(uint_t* cnt, int blk) {
    __hip_atomic_fetch_add(&cnt[(blk & 15) * 32], 1u, __ATOMIC_RELEASE, __HIP_MEMORY_SCOPE_AGENT);
}
__device__ inline void bar_wait(uint_t* cnt, uint_t tgt) {
    if (threadIdx.x == 0) {
        for (;;) {
            uint_t s = 0;
            #pragma unroll
            for (int i = 0; i < 16; ++i)
                s += __hip_atomic_load(&cnt[i * 32], __ATOMIC_RELAXED, __HIP_MEMORY_SCOPE_AGENT);
            if (s >= tgt) break;
            __builtin_amdgcn_s_sleep(2);
        }
        (void)__hip_atomic_load(&cnt[0], __ATOMIC_ACQUIRE, __HIP_MEMORY_SCOPE_AGENT);
    }
    __syncthreads();
}
__device__ inline float aload(const float* p) {
    return __hip_atomic_load(p, __ATOMIC_RELAXED, __HIP_MEMORY_SCOPE_AGENT);
}
__device__ inline void astore(float* p, float v) {
    __hip_atomic_store(p, v, __ATOMIC_RELAXED, __HIP_MEMORY_SCOPE_AGENT);
}

// soft-threshold on a packed bf16 pair
__device__ inline uint_t act2(uint_t v, float lam, float th1, float& cnt_) {
    float lo = __uint_as_float(v << 16);
    float hi = __uint_as_float(v & 0xffff0000u);
    float ml = fabsf(lo), mh = fabsf(hi);
    float fl = th1 * copysignf(fmaxf(ml - lam, 0.f), lo);
    float fh = th1 * copysignf(fmaxf(mh - lam, 0.f), hi);
    cnt_ += ((ml > lam) ? 1.f : 0.f) + ((mh > lam) ? 1.f : 0.f);
    return ((uint_t)f2bf(fl)) | (((uint_t)f2bf(fh)) << 16);
}

// ---------- prep: frag-linear bf16 layouts + zero barrier shards ----------
// Af: [L][tile32][k2(2)][quad4][m16][8]  (fwd B-frags; wave reads 1KiB contiguous)
// At: [L][ft3][ks16][quad4][m16][8]      (bwd B-frags)
// Df: [ft3][ks16][quad4][m16][8]         (final B-frags)
__global__ __launch_bounds__(256) void k_pre(
    const float* __restrict__ Ar, const float* __restrict__ Ai,
    const float* __restrict__ Dr, const float* __restrict__ Di,
    ushort_t* __restrict__ Afr, ushort_t* __restrict__ Afi,
    ushort_t* __restrict__ Atr, ushort_t* __restrict__ Ati,
    ushort_t* __restrict__ Dfr, ushort_t* __restrict__ Dfi,
    uint_t* __restrict__ cnt)
{
    const int gt = blockIdx.x * 256 + threadIdx.x;
    const int gs = gridDim.x * 256;
    if (gt < 512) cnt[gt] = 0u;
    for (int idx = gt; idx < L_ * 32768; idx += gs) {
        int j = idx & 7, rest = idx >> 3;
        int mm = rest & 15; rest >>= 4;
        int qq = rest & 3;  rest >>= 2;
        int k2 = rest & 1;  rest >>= 1;
        int tile = rest & 31;
        int l = rest >> 5;
        int t = tile * 16 + mm, k = k2 * 32 + qq * 8 + j;
        float vr = 0.f, vi = 0.f;
        if (k < 48) { int g = l * 24576 + t * 48 + k; vr = Ar[g]; vi = Ai[g]; }
        Afr[idx] = f2bf(vr); Afi[idx] = f2bf(vi);
    }
    for (int idx = gt; idx < L_ * 24576; idx += gs) {
        int j = idx & 7, rest = idx >> 3;
        int mm = rest & 15; rest >>= 4;
        int qq = rest & 3;  rest >>= 2;
        int ks = rest & 15; rest >>= 4;
        int ft = rest % 3;
        int l = rest / 3;
        int f = ft * 16 + mm, k = ks * 32 + qq * 8 + j;
        int g = l * 24576 + k * 48 + f;
        Atr[idx] = f2bf(Ar[g]); Ati[idx] = f2bf(Ai[g]);
    }
    for (int idx = gt; idx < 24576; idx += gs) {
        int j = idx & 7, rest = idx >> 3;
        int mm = rest & 15; rest >>= 4;
        int qq = rest & 3;  rest >>= 2;
        int ks = rest & 15;
        int ft = rest >> 4;
        int f = ft * 16 + mm, k = ks * 32 + qq * 8 + j;
        Dfr[idx] = f2bf(Dr[k * 48 + f]); Dfi[idx] = f2bf(Di[k * 48 + f]);
    }
}

// ---------- persistent cooperative kernel ----------
// 512 blocks x 512 threads (2 blocks/CU); block owns rows [blk*16,+16); z fp32 + H bf16 in LDS.
__global__ __launch_bounds__(THR, 4) void k_lamp(
    const float* __restrict__ u,
    const ushort_t* __restrict__ Afr, const ushort_t* __restrict__ Afi,
    const ushort_t* __restrict__ Atr, const ushort_t* __restrict__ Ati,
    const ushort_t* __restrict__ Dfr, const ushort_t* __restrict__ Dfi,
    const float* __restrict__ th,
    float* part_sig, float* part_r, float* part_i, uint_t* cnt,
    float* __restrict__ out)
{
    extern __shared__ char dyn[];
    float*    pR   = (float*)dyn;                  // [4][3][16][17] 13056 B
    float*    pI   = pR + 4 * 3 * 16 * 17;         // 13056 B
    float*    zreL = pI + 4 * 3 * 16 * 17;         // 3328 B
    float*    zimL = zreL + RPB * ZS;              // 3328 B
    float*    red8 = zimL + RPB * ZS;              // 64 B
    ushort_t* HreL = (ushort_t*)(red8 + 16);       // 16640 B
    ushort_t* HimL = HreL + RPB * HST;             // 16640 B  => 66112 B

    const int tid = threadIdx.x, blk = blockIdx.x;
    const int row0 = blk * RPB;
    const int wave = tid >> 6, lane = tid & 63;
    const int quad = lane >> 4, m = lane & 15;
    const int kq = wave;                            // bwd/final: K-eighth
    const float2* u2 = (const float2*)u;
    uint_t tgt = 0;

    // prologue: u -> z LDS, sigma partial
    float acc = 0.f;
    #pragma unroll
    for (int k2 = 0; k2 < 2; ++k2) {
        int j = tid + k2 * THR;
        if (j < RPB * F_) {
            int r = j / 48, c = j - r * 48;
            float2 v = u2[(row0 + r) * 48 + c];
            zreL[r * ZS + c] = v.x; zimL[r * ZS + c] = v.y;
            acc += v.x * v.x + v.y * v.y;
        }
    }
    float s0 = blk_sum(acc, red8);
    if (tid == 0) { astore(&part_sig[blk], s0); bar_add(cnt, blk); }
    tgt += NBLK;

    for (int l = 0; l < L_; ++l) {
        // z A-frags from LDS fp32 (K=48 padded to 64)
        const float* zpr = zreL + m * ZS;
        const float* zpi = zimL + m * ZS;
        short8 zr0 = pack8(*(const float4*)(zpr + quad * 8), *(const float4*)(zpr + quad * 8 + 4));
        short8 zi0 = pack8(*(const float4*)(zpi + quad * 8), *(const float4*)(zpi + quad * 8 + 4));
        short8 zr1 = {0,0,0,0,0,0,0,0}, zi1 = {0,0,0,0,0,0,0,0};
        if (quad < 2) {
            zr1 = pack8(*(const float4*)(zpr + 32 + quad * 8), *(const float4*)(zpr + 36 + quad * 8));
            zi1 = pack8(*(const float4*)(zpi + 32 + quad * 8), *(const float4*)(zpi + 36 + quad * 8));
        }
        short8 zin0 = negbf(zi0), zin1 = negbf(zi1);

        // forward GEMM; store R = Hold + Z to H LDS (activation deferred past barrier)
        const ushort_t* Aflr = Afr + (size_t)l * 32768;
        const ushort_t* Afli = Afi + (size_t)l * 32768;
        #pragma unroll
        for (int ct = 0; ct < 4; ++ct) {
            const int tile = wave * 4 + ct;
            const ushort_t* rp = Aflr + (size_t)(tile * 2) * 512 + lane * 8;
            const ushort_t* ip = Afli + (size_t)(tile * 2) * 512 + lane * 8;
            short8 ar0 = *(const short8*)rp;
            short8 ar1 = *(const short8*)(rp + 512);
            short8 ai0 = *(const short8*)ip;
            short8 ai1 = *(const short8*)(ip + 512);
            f32x4 accR = {0.f,0.f,0.f,0.f}, accI = {0.f,0.f,0.f,0.f};
            accR = MFMA(zr0, ar0, accR);
            accR = MFMA(zr1, ar1, accR);
            accR = MFMA(zin0, ai0, accR);
            accR = MFMA(zin1, ai1, accR);
            accI = MFMA(zr0, ai0, accI);
            accI = MFMA(zr1, ai1, accI);
            accI = MFMA(zi0, ar0, accI);
            accI = MFMA(zi1, ar1, accI);
            const int t = tile * 16 + m;
            #pragma unroll
            for (int reg = 0; reg < 4; ++reg) {
                const int lr = quad * 4 + reg;
                float Rr = accR[reg], Ri = accI[reg];
                if (l > 0) { Rr += bf2f(HreL[lr * HST + t]); Ri += bf2f(HimL[lr * HST + t]); }
                HreL[lr * HST + t] = f2bf(Rr);
                HimL[lr * HST + t] = f2bf(Ri);
            }
        }

        // sigma barrier (hidden behind the GEMM above) + lambda
        bar_wait(cnt, tgt);
        float ssum = blk_sum(aload(&part_sig[tid]), red8);
        const float lam = th[l * 3] * sqrtf(ssum * (1.0f / 48.0f));
        const float th1 = th[l * 3 + 1];

        // vectorized activation pass over H LDS (R -> Hn), count partials
        float cr = 0.f, ci = 0.f;
        uint4* Hr4 = (uint4*)HreL;
        uint4* Hi4 = (uint4*)HimL;
        #pragma unroll
        for (int k2 = 0; k2 < 2; ++k2) {
            int j = tid + k2 * THR;          // 0..1023
            int r = j >> 6, c4 = j & 63;     // 64 uint4 of data per row (65 incl pad)
            uint4* pr = Hr4 + r * 65 + c4;
            uint4* pi = Hi4 + r * 65 + c4;
            uint4 xr = *pr, xi = *pi;
            xr.x = act2(xr.x, lam, th1, cr); xr.y = act2(xr.y, lam, th1, cr);
            xr.z = act2(xr.z, lam, th1, cr); xr.w = act2(xr.w, lam, th1, cr);
            xi.x = act2(xi.x, lam, th1, ci); xi.y = act2(xi.y, lam, th1, ci);
            xi.z = act2(xi.z, lam, th1, ci); xi.w = act2(xi.w, lam, th1, ci);
            *pr = xr; *pi = xi;
        }

        if (l == L_ - 1) { __syncthreads(); break; }

        float csr = blk_sum(cr, red8);       // also publishes Hn block-wide
        if (tid == 0) astore(&part_r[blk], csr);
        float csi = blk_sum(ci, red8);
        if (tid == 0) { astore(&part_i[blk], csi); bar_add(cnt, blk); }
        tgt += NBLK;

        // backward GEMM: h = Hn @ A; wave kq does K-eighth kq over the 16 rows
        const ushort_t* Atlr = Atr + (size_t)l * 24576;
        const ushort_t* Atli = Ati + (size_t)l * 24576;
        f32x4 aR[3], aI[3];
        #pragma unroll
        for (int q = 0; q < 3; ++q) { aR[q] = (f32x4){0,0,0,0}; aI[q] = (f32x4){0,0,0,0}; }
        #pragma unroll
        for (int ks = 0; ks < 2; ++ks) {
            const int ksa = kq * 2 + ks;
            const int k0 = ksa * 32 + quad * 8;
            short8 hr = *(const short8*)&HreL[m * HST + k0];
            short8 hi = *(const short8*)&HimL[m * HST + k0];
            short8 hin = negbf(hi);
            #pragma unroll
            for (int ft = 0; ft < 3; ++ft) {
                short8 br = *(const short8*)(Atlr + (size_t)((ft * 16 + ksa) * 64 + lane) * 8);
                short8 bi = *(const short8*)(Atli + (size_t)((ft * 16 + ksa) * 64 + lane) * 8);
                aR[ft] = MFMA(hr, br, aR[ft]);
                aR[ft] = MFMA(hin, bi, aR[ft]);
                aI[ft] = MFMA(hr, bi, aI[ft]);
                aI[ft] = MFMA(hi, br, aI[ft]);
            }
        }
        // two-phase K-partial combine: slot s = kq&3; kq<4 store, kq>=4 add
        {
            const int s = kq & 3;
            if (kq < 4) {
                #pragma unroll
                for (int ft = 0; ft < 3; ++ft)
                    #pragma unroll
                    for (int reg = 0; reg < 4; ++reg) {
                        pR[((s * 3 + ft) * 16 + quad * 4 + reg) * 17 + m] = aR[ft][reg];
                        pI[((s * 3 + ft) * 16 + quad * 4 + reg) * 17 + m] = aI[ft][reg];
                    }
            }
            __syncthreads();
            if (kq >= 4) {
                #pragma unroll
                for (int ft = 0; ft < 3; ++ft)
                    #pragma unroll
                    for (int reg = 0; reg < 4; ++reg) {
                        pR[((s * 3 + ft) * 16 + quad * 4 + reg) * 17 + m] += aR[ft][reg];
                        pI[((s * 3 + ft) * 16 + quad * 4 + reg) * 17 + m] += aI[ft][reg];
                    }
            }
        }

        // b barrier (hidden behind backward GEMM); its syncthreads publishes pR/pI
        bar_wait(cnt, tgt);
        float bsr = blk_sum(aload(&part_r[tid]), red8);
        float bsi = blk_sum(aload(&part_i[tid]), red8);
        const float bre = th1 * bsr * (1.0f / 48.0f);
        const float bim = th1 * bsi * (1.0f / 48.0f);

        // z update + sigma partial
        float nrm = 0.f;
        #pragma unroll
        for (int k2 = 0; k2 < 2; ++k2) {
            int j = tid + k2 * THR;
            if (j < RPB * F_) {
                int r = j / 48, f = j - r * 48;
                int lr = r & 15, ft = f >> 4, c = f & 15;
                float hR = 0.f, hI = 0.f;
                #pragma unroll
                for (int q = 0; q < 4; ++q) {
                    hR += pR[((q * 3 + ft) * 16 + lr) * 17 + c];
                    hI += pI[((q * 3 + ft) * 16 + lr) * 17 + c];
                }
                float2 uv = u2[(row0 + r) * 48 + f];
                float zr = zreL[r * ZS + f], zi = zimL[r * ZS + f];
                float znr = uv.x - hR + bre * zr;
                float zni = uv.y - hI + bim * zi;
                zreL[r * ZS + f] = znr; zimL[r * ZS + f] = zni;
                nrm += znr * znr + zni * zni;
            }
        }
        float ns = blk_sum(nrm, red8);
        if (tid == 0) { astore(&part_sig[blk], ns); bar_add(cnt, blk); }
        tgt += NBLK;
    }

    // final: out = Hn(LDS) @ DFT  (wave kq, K-split 8-way, two-phase combine)
    f32x4 fR[3], fI[3];
    #pragma unroll
    for (int q = 0; q < 3; ++q) { fR[q] = (f32x4){0,0,0,0}; fI[q] = (f32x4){0,0,0,0}; }
    #pragma unroll
    for (int ks = 0; ks < 2; ++ks) {
        const int ksa = kq * 2 + ks;
        const int k0 = ksa * 32 + quad * 8;
        short8 hr = *(const short8*)&HreL[m * HST + k0];
        short8 hi = *(const short8*)&HimL[m * HST + k0];
        short8 hin = negbf(hi);
        #pragma unroll
        for (int ft = 0; ft < 3; ++ft) {
            short8 br = *(const short8*)(Dfr + (size_t)((ft * 16 + ksa) * 64 + lane) * 8);
            short8 bi = *(const short8*)(Dfi + (size_t)((ft * 16 + ksa) * 64 + lane) * 8);
            fR[ft] = MFMA(hr, br, fR[ft]);
            fR[ft] = MFMA(hin, bi, fR[ft]);
            fI[ft] = MFMA(hr, bi, fI[ft]);
            fI[ft] = MFMA(hi, br, fI[ft]);
        }
    }
    {
        const int s = kq & 3;
        if (kq < 4) {
            #pragma unroll
            for (int ft = 0; ft < 3; ++ft)
                #pragma unroll
                for (int reg = 0; reg < 4; ++reg) {
                    pR[((s * 3 + ft) * 16 + quad * 4 + reg) * 17 + m] = fR[ft][reg];
                    pI[((s * 3 + ft) * 16 + quad * 4 + reg) * 17 + m] = fI[ft][reg];
                }
        }
        __syncthreads();
        if (kq >= 4) {
            #pragma unroll
            for (int ft = 0; ft < 3; ++ft)
                #pragma unroll
                for (int reg = 0; reg < 4; ++reg) {
                    pR[((s * 3 + ft) * 16 + quad * 4 + reg) * 17 + m] += fR[ft][reg];
                    pI[((s * 3 + ft) * 16 + quad * 4 + reg) * 17 + m] += fI[ft][reg];
                }
        }
    }
    __syncthreads();
    float2* out2 = (float2*)out;
    #pragma unroll
    for (int k2 = 0; k2 < 2; ++k2) {
        int j = tid + k2 * THR;
        if (j < RPB * F_) {
            int r = j / 48, f = j - r * 48;
            int lr = r & 15, ft = f >> 4, c = f & 15;
            float hR = 0.f, hI = 0.f;
            #pragma unroll
            for (int q = 0; q < 4; ++q) {
                hR += pR[((q * 3 + ft) * 16 + lr) * 17 + c];
                hI += pI[((q * 3 + ft) * 16 + lr) * 17 + c];
            }
            out2[(row0 + r) * 48 + f] = make_float2(hR, hI);
        }
    }
}

extern "C" void kernel_launch(void* const* d_in, const int* in_sizes, int n_in,
                              void* d_out, int out_size, void* d_ws, size_t ws_size,
                              hipStream_t stream) {
    (void)in_sizes; (void)n_in; (void)out_size; (void)ws_size;
    const float* u  = (const float*)d_in[0];
    const float* Ar = (const float*)d_in[1];
    const float* Ai = (const float*)d_in[2];
    const float* th = (const float*)d_in[3];
    const float* Dr = (const float*)d_in[4];
    const float* Di = (const float*)d_in[5];
    float* out = (float*)d_out;

    char* p = (char*)d_ws;
    auto alloc = [&](size_t bytes) -> char* {
        char* r = p;
        p += (bytes + 255) & ~(size_t)255;
        return r;
    };
    float*    part_sig = (float*)alloc(NBLK * 4);
    float*    part_r   = (float*)alloc(NBLK * 4);
    float*    part_i   = (float*)alloc(NBLK * 4);
    uint_t*   cnt      = (uint_t*)alloc(512 * 4);   // 16 shards on 128B lines
    ushort_t* Afr = (ushort_t*)alloc((size_t)L_ * 32768 * 2);
    ushort_t* Afi = (ushort_t*)alloc((size_t)L_ * 32768 * 2);
    ushort_t* Atr = (ushort_t*)alloc((size_t)L_ * 24576 * 2);
    ushort_t* Ati = (ushort_t*)alloc((size_t)L_ * 24576 * 2);
    ushort_t* Dfr = (ushort_t*)alloc((size_t)24576 * 2);
    ushort_t* Dfi = (ushort_t*)alloc((size_t)24576 * 2);

    k_pre<<<256, 256, 0, stream>>>(Ar, Ai, Dr, Di, Afr, Afi, Atr, Ati, Dfr, Dfi, cnt);

    const uint_t lds_bytes = 66112;
    hipFuncSetAttribute((const void*)k_lamp,
                        hipFuncAttributeMaxDynamicSharedMemorySize, (int)lds_bytes);
    void* args[] = { (void*)&u, (void*)&Afr, (void*)&Afi, (void*)&Atr, (void*)&Ati,
                     (void*)&Dfr, (void*)&Dfi, (void*)&th,
                     (void*)&part_sig, (void*)&part_r, (void*)&part_i,
                     (void*)&cnt, (void*)&out };
    hipLaunchCooperativeKernel((void*)k_lamp, dim3(NBLK), dim3(THR), args,
                               lds_bytes, stream);
}

// Round 9
// 292.145 us; speedup vs baseline: 4.0287x; 1.0593x over previous
//
#include <hip/hip_runtime.h>
#include <hip/hip_bf16.h>
#include <math.h>

#define B_   8192
#define F_   48
#define T_   512
#define L_   8
#define NBLK 512
#define THR  256
#define NW   4           // waves per block
#define RPB  16          // rows per block
#define HST  520         // H LDS row stride in shorts (1040B; 65 uint4)
#define ZS   52          // z LDS row stride in floats

typedef unsigned short ushort_t;
typedef unsigned int   uint_t;
typedef __attribute__((ext_vector_type(8))) short short8;
typedef __attribute__((ext_vector_type(4))) float f32x4;

#define MFMA(a,b,c) __builtin_amdgcn_mfma_f32_16x16x32_bf16(a,b,c,0,0,0)

__device__ inline ushort_t f2bf(float x) {
    __hip_bfloat16 h = __float2bfloat16(x);
    return *reinterpret_cast<ushort_t*>(&h);
}
__device__ inline float bf2f(ushort_t x) {
    __hip_bfloat16 h;
    *reinterpret_cast<ushort_t*>(&h) = x;
    return __bfloat162float(h);
}
__device__ inline short8 negbf(short8 v) {
    short8 r;
    #pragma unroll
    for (int i = 0; i < 8; ++i) r[i] = v[i] ^ (short)0x8000;
    return r;
}
__device__ inline short8 pack8(float4 a, float4 b) {
    short8 r;
    r[0]=(short)f2bf(a.x); r[1]=(short)f2bf(a.y); r[2]=(short)f2bf(a.z); r[3]=(short)f2bf(a.w);
    r[4]=(short)f2bf(b.x); r[5]=(short)f2bf(b.y); r[6]=(short)f2bf(b.z); r[7]=(short)f2bf(b.w);
    return r;
}

// block-wide multi-value reduce: wave butterfly, leaders -> redL[q*NW + wave]
template<int NQ>
__device__ inline void reduce_vals(float* v, float* redL, int wave, int lane) {
    #pragma unroll
    for (int s = 32; s > 0; s >>= 1)
        #pragma unroll
        for (int q = 0; q < NQ; ++q) v[q] += __shfl_xor(v[q], s, 64);
    __syncthreads();                  // protect prior redL use
    if (lane == 0)
        #pragma unroll
        for (int q = 0; q < NQ; ++q) redL[q * NW + wave] = v[q];
    __syncthreads();
}

// sharded barrier: 16 counters on separate 128B lines
__device__ inline void bar_add(uint_t* cnt, int blk) {
    __hip_atomic_fetch_add(&cnt[(blk & 15) * 32], 1u, __ATOMIC_RELEASE, __HIP_MEMORY_SCOPE_AGENT);
}
__device__ inline void bar_wait(uint_t* cnt, uint_t tgt) {
    if (threadIdx.x == 0) {
        for (;;) {
            uint_t s = 0;
            #pragma unroll
            for (int i = 0; i < 16; ++i)
                s += __hip_atomic_load(&cnt[i * 32], __ATOMIC_RELAXED, __HIP_MEMORY_SCOPE_AGENT);
            if (s >= tgt) break;
            __builtin_amdgcn_s_sleep(2);
        }
        (void)__hip_atomic_load(&cnt[0], __ATOMIC_ACQUIRE, __HIP_MEMORY_SCOPE_AGENT);
    }
    __syncthreads();
}
__device__ inline float aload(const float* p) {
    return __hip_atomic_load(p, __ATOMIC_RELAXED, __HIP_MEMORY_SCOPE_AGENT);
}
__device__ inline void astore(float* p, float v) {
    __hip_atomic_store(p, v, __ATOMIC_RELAXED, __HIP_MEMORY_SCOPE_AGENT);
}

// soft-threshold on a packed bf16 pair
__device__ inline uint_t act2(uint_t v, float lam, float th1, float& cnt_) {
    float lo = __uint_as_float(v << 16);
    float hi = __uint_as_float(v & 0xffff0000u);
    float ml = fabsf(lo), mh = fabsf(hi);
    float fl = th1 * copysignf(fmaxf(ml - lam, 0.f), lo);
    float fh = th1 * copysignf(fmaxf(mh - lam, 0.f), hi);
    cnt_ += ((ml > lam) ? 1.f : 0.f) + ((mh > lam) ? 1.f : 0.f);
    return ((uint_t)f2bf(fl)) | (((uint_t)f2bf(fh)) << 16);
}

// ---------- prep: frag-linear bf16 layouts + zero barrier shards ----------
// Af: [L][tile32][k2(2)][quad4][m16][8]  (fwd B-frags; wave reads contiguous)
// At: [L][ft3][ks16][quad4][m16][8]      (bwd B-frags)
// Df: [ft3][ks16][quad4][m16][8]         (final B-frags)
__global__ __launch_bounds__(256) void k_pre(
    const float* __restrict__ Ar, const float* __restrict__ Ai,
    const float* __restrict__ Dr, const float* __restrict__ Di,
    ushort_t* __restrict__ Afr, ushort_t* __restrict__ Afi,
    ushort_t* __restrict__ Atr, ushort_t* __restrict__ Ati,
    ushort_t* __restrict__ Dfr, ushort_t* __restrict__ Dfi,
    uint_t* __restrict__ cnt)
{
    const int gt = blockIdx.x * 256 + threadIdx.x;
    const int gs = gridDim.x * 256;
    if (gt < 512) cnt[gt] = 0u;
    for (int idx = gt; idx < L_ * 32768; idx += gs) {
        int j = idx & 7, rest = idx >> 3;
        int mm = rest & 15; rest >>= 4;
        int qq = rest & 3;  rest >>= 2;
        int k2 = rest & 1;  rest >>= 1;
        int tile = rest & 31;
        int l = rest >> 5;
        int t = tile * 16 + mm, k = k2 * 32 + qq * 8 + j;
        float vr = 0.f, vi = 0.f;
        if (k < 48) { int g = l * 24576 + t * 48 + k; vr = Ar[g]; vi = Ai[g]; }
        Afr[idx] = f2bf(vr); Afi[idx] = f2bf(vi);
    }
    for (int idx = gt; idx < L_ * 24576; idx += gs) {
        int j = idx & 7, rest = idx >> 3;
        int mm = rest & 15; rest >>= 4;
        int qq = rest & 3;  rest >>= 2;
        int ks = rest & 15; rest >>= 4;
        int ft = rest % 3;
        int l = rest / 3;
        int f = ft * 16 + mm, k = ks * 32 + qq * 8 + j;
        int g = l * 24576 + k * 48 + f;
        Atr[idx] = f2bf(Ar[g]); Ati[idx] = f2bf(Ai[g]);
    }
    for (int idx = gt; idx < 24576; idx += gs) {
        int j = idx & 7, rest = idx >> 3;
        int mm = rest & 15; rest >>= 4;
        int qq = rest & 3;  rest >>= 2;
        int ks = rest & 15;
        int ft = rest >> 4;
        int f = ft * 16 + mm, k = ks * 32 + qq * 8 + j;
        Dfr[idx] = f2bf(Dr[k * 48 + f]); Dfi[idx] = f2bf(Di[k * 48 + f]);
    }
}

// forward GEMM: R(= Hold + z@A^T) -> H LDS. Ends with a syncthreads.
__device__ inline void fwd_gemm(const ushort_t* Aflr, const ushort_t* Afli,
    const float* zreL, const float* zimL, ushort_t* HreL, ushort_t* HimL,
    int wave, int lane, int quad, int m, bool addH)
{
    const float* zpr = zreL + m * ZS;
    const float* zpi = zimL + m * ZS;
    short8 zr0 = pack8(*(const float4*)(zpr + quad * 8), *(const float4*)(zpr + quad * 8 + 4));
    short8 zi0 = pack8(*(const float4*)(zpi + quad * 8), *(const float4*)(zpi + quad * 8 + 4));
    short8 zr1 = {0,0,0,0,0,0,0,0}, zi1 = {0,0,0,0,0,0,0,0};
    if (quad < 2) {
        zr1 = pack8(*(const float4*)(zpr + 32 + quad * 8), *(const float4*)(zpr + 36 + quad * 8));
        zi1 = pack8(*(const float4*)(zpi + 32 + quad * 8), *(const float4*)(zpi + 36 + quad * 8));
    }
    short8 zin0 = negbf(zi0), zin1 = negbf(zi1);
    #pragma unroll
    for (int ct = 0; ct < 8; ++ct) {
        const int tile = wave * 8 + ct;
        const ushort_t* rp = Aflr + (size_t)(tile * 2) * 512 + lane * 8;
        const ushort_t* ip = Afli + (size_t)(tile * 2) * 512 + lane * 8;
        short8 ar0 = *(const short8*)rp;
        short8 ar1 = *(const short8*)(rp + 512);
        short8 ai0 = *(const short8*)ip;
        short8 ai1 = *(const short8*)(ip + 512);
        f32x4 accR = {0.f,0.f,0.f,0.f}, accI = {0.f,0.f,0.f,0.f};
        accR = MFMA(zr0, ar0, accR);
        accR = MFMA(zr1, ar1, accR);
        accR = MFMA(zin0, ai0, accR);
        accR = MFMA(zin1, ai1, accR);
        accI = MFMA(zr0, ai0, accI);
        accI = MFMA(zr1, ai1, accI);
        accI = MFMA(zi0, ar0, accI);
        accI = MFMA(zi1, ar1, accI);
        const int t = tile * 16 + m;
        #pragma unroll
        for (int reg = 0; reg < 4; ++reg) {
            const int lr = quad * 4 + reg;
            float Rr = accR[reg], Ri = accI[reg];
            if (addH) { Rr += bf2f(HreL[lr * HST + t]); Ri += bf2f(HimL[lr * HST + t]); }
            HreL[lr * HST + t] = f2bf(Rr);
            HimL[lr * HST + t] = f2bf(Ri);
        }
    }
    __syncthreads();
}

// ---------- persistent cooperative kernel ----------
// 512 blocks x 256 threads (2 blocks/CU: 53KB LDS, reg budget 256 -> no spill);
// block owns rows [blk*16,+16); one barrier per layer (sigma fused via expansion).
__global__ __launch_bounds__(THR, 2) void k_lamp(
    const float* __restrict__ u,
    const ushort_t* __restrict__ Afr, const ushort_t* __restrict__ Afi,
    const ushort_t* __restrict__ Atr, const ushort_t* __restrict__ Ati,
    const ushort_t* __restrict__ Dfr, const ushort_t* __restrict__ Dfi,
    const float* __restrict__ th,
    float* part, uint_t* cnt,
    float* __restrict__ out)
{
    extern __shared__ char dyn[];
    float*    pR   = (float*)dyn;                  // [2][3][16][17] 6528 B
    float*    pI   = pR + 2 * 3 * 16 * 17;         // 6528 B
    float*    zreL = pI + 2 * 3 * 16 * 17;         // 3328 B
    float*    zimL = zreL + RPB * ZS;              // 3328 B
    float*    redL = zimL + RPB * ZS;              // 128 B
    ushort_t* HreL = (ushort_t*)(redL + 32);       // 16640 B
    ushort_t* HimL = HreL + RPB * HST;             // 16640 B  => 53120 B

    const int tid = threadIdx.x, blk = blockIdx.x;
    const int row0 = blk * RPB;
    const int wave = tid >> 6, lane = tid & 63;
    const int quad = lane >> 4, m = lane & 15;
    const int kq = wave;                            // bwd/final: K-quarter
    const float2* u2 = (const float2*)u;
    uint_t tgt = NBLK;

    // prologue: u -> z LDS, ||z0||^2 partial, arrive init barrier
    {
        float acc = 0.f;
        #pragma unroll
        for (int k3 = 0; k3 < 3; ++k3) {
            int j = tid + k3 * THR;
            int r = j / 48, c = j - r * 48;
            float2 v = u2[(row0 + r) * 48 + c];
            zreL[r * ZS + c] = v.x; zimL[r * ZS + c] = v.y;
            acc += v.x * v.x + v.y * v.y;
        }
        float v[1] = {acc};
        reduce_vals<1>(v, redL, wave, lane);
        if (tid == 0) {
            float t0 = redL[0] + redL[1] + redL[2] + redL[3];
            astore(&part[blk * 8], t0);
        }
        __syncthreads();
        if (tid == 0) bar_add(cnt, blk);
    }

    // forward layer 0 (hides init barrier)
    fwd_gemm(Afr, Afi, zreL, zimL, HreL, HimL, wave, lane, quad, m, false);

    // init barrier -> sigma_0
    bar_wait(cnt, tgt);
    float lam, th1;
    {
        float v[1];
        v[0] = aload(&part[tid * 8]) + aload(&part[(tid + 256) * 8]);
        reduce_vals<1>(v, redL, wave, lane);
        float sig2 = redL[0] + redL[1] + redL[2] + redL[3];
        lam = th[0] * sqrtf(sig2 * (1.0f / 48.0f));
        th1 = th[1];
    }

    float dR[3], dI[3];
    for (int l = 0; l < L_; ++l) {
        // activation pass (R -> Hn in LDS), counts
        float cr = 0.f, ci = 0.f;
        {
            uint4* Hr4 = (uint4*)HreL;
            uint4* Hi4 = (uint4*)HimL;
            #pragma unroll
            for (int k4 = 0; k4 < 4; ++k4) {
                int j = tid + k4 * THR;          // 0..1023
                int r = j >> 6, c4 = j & 63;
                uint4* pr = Hr4 + r * 65 + c4;
                uint4* pi = Hi4 + r * 65 + c4;
                uint4 xr = *pr, xi = *pi;
                xr.x = act2(xr.x, lam, th1, cr); xr.y = act2(xr.y, lam, th1, cr);
                xr.z = act2(xr.z, lam, th1, cr); xr.w = act2(xr.w, lam, th1, cr);
                xi.x = act2(xi.x, lam, th1, ci); xi.y = act2(xi.y, lam, th1, ci);
                xi.z = act2(xi.z, lam, th1, ci); xi.w = act2(xi.w, lam, th1, ci);
                *pr = xr; *pi = xi;
            }
        }
        __syncthreads();
        if (l == L_ - 1) break;

        // backward GEMM: h = Hn @ A; wave kq does K-quarter kq
        {
            const ushort_t* Atlr = Atr + (size_t)l * 24576;
            const ushort_t* Atli = Ati + (size_t)l * 24576;
            f32x4 aR[3], aI[3];
            #pragma unroll
            for (int q = 0; q < 3; ++q) { aR[q] = (f32x4){0,0,0,0}; aI[q] = (f32x4){0,0,0,0}; }
            #pragma unroll
            for (int ks = 0; ks < 4; ++ks) {
                const int ksa = kq * 4 + ks;
                const int k0 = ksa * 32 + quad * 8;
                short8 hr = *(const short8*)&HreL[m * HST + k0];
                short8 hi = *(const short8*)&HimL[m * HST + k0];
                short8 hin = negbf(hi);
                #pragma unroll
                for (int ft = 0; ft < 3; ++ft) {
                    short8 br = *(const short8*)(Atlr + (size_t)((ft * 16 + ksa) * 64 + lane) * 8);
                    short8 bi = *(const short8*)(Atli + (size_t)((ft * 16 + ksa) * 64 + lane) * 8);
                    aR[ft] = MFMA(hr, br, aR[ft]);
                    aR[ft] = MFMA(hin, bi, aR[ft]);
                    aI[ft] = MFMA(hr, bi, aI[ft]);
                    aI[ft] = MFMA(hi, br, aI[ft]);
                }
            }
            // two-phase K-partial combine: slot s = kq&1; kq<2 store, kq>=2 add
            const int s = kq & 1;
            if (kq < 2) {
                #pragma unroll
                for (int ft = 0; ft < 3; ++ft)
                    #pragma unroll
                    for (int reg = 0; reg < 4; ++reg) {
                        pR[((s * 3 + ft) * 16 + quad * 4 + reg) * 17 + m] = aR[ft][reg];
                        pI[((s * 3 + ft) * 16 + quad * 4 + reg) * 17 + m] = aI[ft][reg];
                    }
            }
            __syncthreads();
            if (kq >= 2) {
                #pragma unroll
                for (int ft = 0; ft < 3; ++ft)
                    #pragma unroll
                    for (int reg = 0; reg < 4; ++reg) {
                        pR[((s * 3 + ft) * 16 + quad * 4 + reg) * 17 + m] += aR[ft][reg];
                        pI[((s * 3 + ft) * 16 + quad * 4 + reg) * 17 + m] += aI[ft][reg];
                    }
            }
            __syncthreads();
        }

        // S-pass: d = u - h kept in regs; expansion sums for ||z_{l+1}||^2
        float S1 = 0.f, S2r = 0.f, S2i = 0.f, S3r = 0.f, S3i = 0.f;
        #pragma unroll
        for (int k3 = 0; k3 < 3; ++k3) {
            int j = tid + k3 * THR;
            int r = j / 48, f = j - r * 48;
            int ft = f >> 4, c = f & 15;
            float hR = pR[(ft * 16 + r) * 17 + c] + pR[((3 + ft) * 16 + r) * 17 + c];
            float hI = pI[(ft * 16 + r) * 17 + c] + pI[((3 + ft) * 16 + r) * 17 + c];
            float2 uv = u2[(row0 + r) * 48 + f];
            float zr = zreL[r * ZS + f], zi = zimL[r * ZS + f];
            float dr = uv.x - hR, di = uv.y - hI;
            dR[k3] = dr; dI[k3] = di;
            S1  += dr * dr + di * di;
            S2r += dr * zr; S2i += di * zi;
            S3r += zr * zr; S3i += zi * zi;
        }
        // publish {cr, ci, S1, S2r, S2i, S3r, S3i} and arrive (single barrier/layer)
        {
            float v[7] = {cr, ci, S1, S2r, S2i, S3r, S3i};
            reduce_vals<7>(v, redL, wave, lane);
            if (tid < 7) {
                float t0 = redL[tid * NW] + redL[tid * NW + 1] + redL[tid * NW + 2] + redL[tid * NW + 3];
                astore(&part[blk * 8 + tid], t0);
            }
            __syncthreads();
            if (tid == 0) bar_add(cnt, blk);
            tgt += NBLK;
        }
        bar_wait(cnt, tgt);
        // combine: b_l and sigma_{l+1} in closed form
        float bre, bim;
        {
            float v[7];
            #pragma unroll
            for (int q = 0; q < 7; ++q)
                v[q] = aload(&part[tid * 8 + q]) + aload(&part[(tid + 256) * 8 + q]);
            reduce_vals<7>(v, redL, wave, lane);
            float tot[7];
            #pragma unroll
            for (int q = 0; q < 7; ++q)
                tot[q] = redL[q * NW] + redL[q * NW + 1] + redL[q * NW + 2] + redL[q * NW + 3];
            bre = th1 * tot[0] * (1.0f / 48.0f);
            bim = th1 * tot[1] * (1.0f / 48.0f);
            float sig2 = tot[2] + 2.f * bre * tot[3] + 2.f * bim * tot[4]
                       + bre * bre * tot[5] + bim * bim * tot[6];
            lam = th[(l + 1) * 3] * sqrtf(sig2 * (1.0f / 48.0f));
            th1 = th[(l + 1) * 3 + 1];
        }
        // z update: zn = d + b*z (local)
        #pragma unroll
        for (int k3 = 0; k3 < 3; ++k3) {
            int j = tid + k3 * THR;
            int r = j / 48, f = j - r * 48;
            float zr = zreL[r * ZS + f], zi = zimL[r * ZS + f];
            zreL[r * ZS + f] = dR[k3] + bre * zr;
            zimL[r * ZS + f] = dI[k3] + bim * zi;
        }
        __syncthreads();
        // forward layer l+1
        fwd_gemm(Afr + (size_t)(l + 1) * 32768, Afi + (size_t)(l + 1) * 32768,
                 zreL, zimL, HreL, HimL, wave, lane, quad, m, true);
    }

    // final: out = Hn(LDS) @ DFT (wave kq, 4-way K, two-phase combine)
    {
        f32x4 fR[3], fI[3];
        #pragma unroll
        for (int q = 0; q < 3; ++q) { fR[q] = (f32x4){0,0,0,0}; fI[q] = (f32x4){0,0,0,0}; }
        #pragma unroll
        for (int ks = 0; ks < 4; ++ks) {
            const int ksa = kq * 4 + ks;
            const int k0 = ksa * 32 + quad * 8;
            short8 hr = *(const short8*)&HreL[m * HST + k0];
            short8 hi = *(const short8*)&HimL[m * HST + k0];
            short8 hin = negbf(hi);
            #pragma unroll
            for (int ft = 0; ft < 3; ++ft) {
                short8 br = *(const short8*)(Dfr + (size_t)((ft * 16 + ksa) * 64 + lane) * 8);
                short8 bi = *(const short8*)(Dfi + (size_t)((ft * 16 + ksa) * 64 + lane) * 8);
                fR[ft] = MFMA(hr, br, fR[ft]);
                fR[ft] = MFMA(hin, bi, fR[ft]);
                fI[ft] = MFMA(hr, bi, fI[ft]);
                fI[ft] = MFMA(hi, br, fI[ft]);
            }
        }
        const int s = kq & 1;
        if (kq < 2) {
            #pragma unroll
            for (int ft = 0; ft < 3; ++ft)
                #pragma unroll
                for (int reg = 0; reg < 4; ++reg) {
                    pR[((s * 3 + ft) * 16 + quad * 4 + reg) * 17 + m] = fR[ft][reg];
                    pI[((s * 3 + ft) * 16 + quad * 4 + reg) * 17 + m] = fI[ft][reg];
                }
        }
        __syncthreads();
        if (kq >= 2) {
            #pragma unroll
            for (int ft = 0; ft < 3; ++ft)
                #pragma unroll
                for (int reg = 0; reg < 4; ++reg) {
                    pR[((s * 3 + ft) * 16 + quad * 4 + reg) * 17 + m] += fR[ft][reg];
                    pI[((s * 3 + ft) * 16 + quad * 4 + reg) * 17 + m] += fI[ft][reg];
                }
        }
        __syncthreads();
        float2* out2 = (float2*)out;
        #pragma unroll
        for (int k3 = 0; k3 < 3; ++k3) {
            int j = tid + k3 * THR;
            int r = j / 48, f = j - r * 48;
            int ft = f >> 4, c = f & 15;
            float hR = pR[(ft * 16 + r) * 17 + c] + pR[((3 + ft) * 16 + r) * 17 + c];
            float hI = pI[(ft * 16 + r) * 17 + c] + pI[((3 + ft) * 16 + r) * 17 + c];
            out2[(row0 + r) * 48 + f] = make_float2(hR, hI);
        }
    }
}

extern "C" void kernel_launch(void* const* d_in, const int* in_sizes, int n_in,
                              void* d_out, int out_size, void* d_ws, size_t ws_size,
                              hipStream_t stream) {
    (void)in_sizes; (void)n_in; (void)out_size; (void)ws_size;
    const float* u  = (const float*)d_in[0];
    const float* Ar = (const float*)d_in[1];
    const float* Ai = (const float*)d_in[2];
    const float* th = (const float*)d_in[3];
    const float* Dr = (const float*)d_in[4];
    const float* Di = (const float*)d_in[5];
    float* out = (float*)d_out;

    char* p = (char*)d_ws;
    auto alloc = [&](size_t bytes) -> char* {
        char* r = p;
        p += (bytes + 255) & ~(size_t)255;
        return r;
    };
    float*    part = (float*)alloc((size_t)NBLK * 8 * 4);   // [512][8]
    uint_t*   cnt  = (uint_t*)alloc(512 * 4);               // 16 shards on 128B lines
    ushort_t* Afr = (ushort_t*)alloc((size_t)L_ * 32768 * 2);
    ushort_t* Afi = (ushort_t*)alloc((size_t)L_ * 32768 * 2);
    ushort_t* Atr = (ushort_t*)alloc((size_t)L_ * 24576 * 2);
    ushort_t* Ati = (ushort_t*)alloc((size_t)L_ * 24576 * 2);
    ushort_t* Dfr = (ushort_t*)alloc((size_t)24576 * 2);
    ushort_t* Dfi = (ushort_t*)alloc((size_t)24576 * 2);

    k_pre<<<256, 256, 0, stream>>>(Ar, Ai, Dr, Di, Afr, Afi, Atr, Ati, Dfr, Dfi, cnt);

    const uint_t lds_bytes = 53120;
    hipFuncSetAttribute((const void*)k_lamp,
                        hipFuncAttributeMaxDynamicSharedMemorySize, (int)lds_bytes);
    void* args[] = { (void*)&u, (void*)&Afr, (void*)&Afi, (void*)&Atr, (void*)&Ati,
                     (void*)&Dfr, (void*)&Dfi, (void*)&th,
                     (void*)&part, (void*)&cnt, (void*)&out };
    hipLaunchCooperativeKernel((void*)k_lamp, dim3(NBLK), dim3(THR), args,
                               lds_bytes, stream);
}

// Round 10
// 279.074 us; speedup vs baseline: 4.2174x; 1.0468x over previous
//
#include <hip/hip_runtime.h>
#include <hip/hip_bf16.h>
#include <math.h>

#define B_   8192
#define F_   48
#define T_   512
#define L_   8
#define NBLK 512
#define THR  256
#define NW   4           // waves per block
#define RPB  16          // rows per block
#define HST  520         // H LDS row stride in shorts (1040B; 65 uint4)
#define ZS   52          // z LDS row stride in floats

typedef unsigned short ushort_t;
typedef unsigned int   uint_t;
typedef __attribute__((ext_vector_type(8))) short short8;
typedef __attribute__((ext_vector_type(4))) float f32x4;

#define MFMA(a,b,c) __builtin_amdgcn_mfma_f32_16x16x32_bf16(a,b,c,0,0,0)

__device__ inline ushort_t f2bf(float x) {
    __hip_bfloat16 h = __float2bfloat16(x);
    return *reinterpret_cast<ushort_t*>(&h);
}
__device__ inline float bf2f(ushort_t x) {
    __hip_bfloat16 h;
    *reinterpret_cast<ushort_t*>(&h) = x;
    return __bfloat162float(h);
}
__device__ inline short8 negbf(short8 v) {
    short8 r;
    #pragma unroll
    for (int i = 0; i < 8; ++i) r[i] = v[i] ^ (short)0x8000;
    return r;
}
__device__ inline short8 pack8(float4 a, float4 b) {
    short8 r;
    r[0]=(short)f2bf(a.x); r[1]=(short)f2bf(a.y); r[2]=(short)f2bf(a.z); r[3]=(short)f2bf(a.w);
    r[4]=(short)f2bf(b.x); r[5]=(short)f2bf(b.y); r[6]=(short)f2bf(b.z); r[7]=(short)f2bf(b.w);
    return r;
}

// block-wide multi-value reduce: wave butterfly, leaders -> redL[q*NW + wave]
template<int NQ>
__device__ inline void reduce_vals(float* v, float* redL, int wave, int lane) {
    #pragma unroll
    for (int s = 32; s > 0; s >>= 1)
        #pragma unroll
        for (int q = 0; q < NQ; ++q) v[q] += __shfl_xor(v[q], s, 64);
    __syncthreads();                  // protect prior redL use / order LDS writes
    if (lane == 0)
        #pragma unroll
        for (int q = 0; q < NQ; ++q) redL[q * NW + wave] = v[q];
    __syncthreads();
}

// sharded barrier: 16 counters on separate 128B lines
__device__ inline void bar_add(uint_t* cnt, int blk) {
    __hip_atomic_fetch_add(&cnt[(blk & 15) * 32], 1u, __ATOMIC_RELEASE, __HIP_MEMORY_SCOPE_AGENT);
}
__device__ inline void bar_wait(uint_t* cnt, uint_t tgt) {
    if (threadIdx.x == 0) {
        for (;;) {
            uint_t s = 0;
            #pragma unroll
            for (int i = 0; i < 16; ++i)
                s += __hip_atomic_load(&cnt[i * 32], __ATOMIC_RELAXED, __HIP_MEMORY_SCOPE_AGENT);
            if (s >= tgt) break;
            __builtin_amdgcn_s_sleep(2);
        }
        (void)__hip_atomic_load(&cnt[0], __ATOMIC_ACQUIRE, __HIP_MEMORY_SCOPE_AGENT);
    }
    __syncthreads();
}
__device__ inline float aload(const float* p) {
    return __hip_atomic_load(p, __ATOMIC_RELAXED, __HIP_MEMORY_SCOPE_AGENT);
}
__device__ inline void astore(float* p, float v) {
    __hip_atomic_store(p, v, __ATOMIC_RELAXED, __HIP_MEMORY_SCOPE_AGENT);
}

// soft-threshold on a packed bf16 pair (layer-0 act pass)
__device__ inline uint_t act2(uint_t v, float lam, float th1, float& cnt_) {
    float lo = __uint_as_float(v << 16);
    float hi = __uint_as_float(v & 0xffff0000u);
    float ml = fabsf(lo), mh = fabsf(hi);
    float fl = th1 * copysignf(fmaxf(ml - lam, 0.f), lo);
    float fh = th1 * copysignf(fmaxf(mh - lam, 0.f), hi);
    cnt_ += ((ml > lam) ? 1.f : 0.f) + ((mh > lam) ? 1.f : 0.f);
    return ((uint_t)f2bf(fl)) | (((uint_t)f2bf(fh)) << 16);
}

// ---------- prep: frag-linear bf16 layouts + zero barrier shards ----------
__global__ __launch_bounds__(256) void k_pre(
    const float* __restrict__ Ar, const float* __restrict__ Ai,
    const float* __restrict__ Dr, const float* __restrict__ Di,
    ushort_t* __restrict__ Afr, ushort_t* __restrict__ Afi,
    ushort_t* __restrict__ Atr, ushort_t* __restrict__ Ati,
    ushort_t* __restrict__ Dfr, ushort_t* __restrict__ Dfi,
    uint_t* __restrict__ cnt)
{
    const int gt = blockIdx.x * 256 + threadIdx.x;
    const int gs = gridDim.x * 256;
    if (gt < 512) cnt[gt] = 0u;
    for (int idx = gt; idx < L_ * 32768; idx += gs) {
        int j = idx & 7, rest = idx >> 3;
        int mm = rest & 15; rest >>= 4;
        int qq = rest & 3;  rest >>= 2;
        int k2 = rest & 1;  rest >>= 1;
        int tile = rest & 31;
        int l = rest >> 5;
        int t = tile * 16 + mm, k = k2 * 32 + qq * 8 + j;
        float vr = 0.f, vi = 0.f;
        if (k < 48) { int g = l * 24576 + t * 48 + k; vr = Ar[g]; vi = Ai[g]; }
        Afr[idx] = f2bf(vr); Afi[idx] = f2bf(vi);
    }
    for (int idx = gt; idx < L_ * 24576; idx += gs) {
        int j = idx & 7, rest = idx >> 3;
        int mm = rest & 15; rest >>= 4;
        int qq = rest & 3;  rest >>= 2;
        int ks = rest & 15; rest >>= 4;
        int ft = rest % 3;
        int l = rest / 3;
        int f = ft * 16 + mm, k = ks * 32 + qq * 8 + j;
        int g = l * 24576 + k * 48 + f;
        Atr[idx] = f2bf(Ar[g]); Ati[idx] = f2bf(Ai[g]);
    }
    for (int idx = gt; idx < 24576; idx += gs) {
        int j = idx & 7, rest = idx >> 3;
        int mm = rest & 15; rest >>= 4;
        int qq = rest & 3;  rest >>= 2;
        int ks = rest & 15;
        int ft = rest >> 4;
        int f = ft * 16 + mm, k = ks * 32 + qq * 8 + j;
        Dfr[idx] = f2bf(Dr[k * 48 + f]); Dfi[idx] = f2bf(Di[k * 48 + f]);
    }
}

// layer-0 forward: R = z@A^T -> H LDS (z fp32 in LDS). Ends with syncthreads.
__device__ inline void fwd_gemm0(const ushort_t* Aflr, const ushort_t* Afli,
    const float* zreL, const float* zimL, ushort_t* HreL, ushort_t* HimL,
    int wave, int lane, int quad, int m)
{
    const float* zpr = zreL + m * ZS;
    const float* zpi = zimL + m * ZS;
    short8 zr0 = pack8(*(const float4*)(zpr + quad * 8), *(const float4*)(zpr + quad * 8 + 4));
    short8 zi0 = pack8(*(const float4*)(zpi + quad * 8), *(const float4*)(zpi + quad * 8 + 4));
    short8 zr1 = {0,0,0,0,0,0,0,0}, zi1 = {0,0,0,0,0,0,0,0};
    if (quad < 2) {
        zr1 = pack8(*(const float4*)(zpr + 32 + quad * 8), *(const float4*)(zpr + 36 + quad * 8));
        zi1 = pack8(*(const float4*)(zpi + 32 + quad * 8), *(const float4*)(zpi + 36 + quad * 8));
    }
    short8 zin0 = negbf(zi0), zin1 = negbf(zi1);
    #pragma unroll
    for (int ct = 0; ct < 8; ++ct) {
        const int tile = wave * 8 + ct;
        const ushort_t* rp = Aflr + (size_t)(tile * 2) * 512 + lane * 8;
        const ushort_t* ip = Afli + (size_t)(tile * 2) * 512 + lane * 8;
        short8 ar0 = *(const short8*)rp;
        short8 ar1 = *(const short8*)(rp + 512);
        short8 ai0 = *(const short8*)ip;
        short8 ai1 = *(const short8*)(ip + 512);
        f32x4 accR = {0.f,0.f,0.f,0.f}, accI = {0.f,0.f,0.f,0.f};
        accR = MFMA(zr0, ar0, accR);
        accR = MFMA(zr1, ar1, accR);
        accR = MFMA(zin0, ai0, accR);
        accR = MFMA(zin1, ai1, accR);
        accI = MFMA(zr0, ai0, accI);
        accI = MFMA(zr1, ai1, accI);
        accI = MFMA(zi0, ar0, accI);
        accI = MFMA(zi1, ar1, accI);
        const int t = tile * 16 + m;
        #pragma unroll
        for (int reg = 0; reg < 4; ++reg) {
            const int lr = quad * 4 + reg;
            HreL[lr * HST + t] = f2bf(accR[reg]);
            HimL[lr * HST + t] = f2bf(accI[reg]);
        }
    }
    __syncthreads();
}

// ---------- persistent cooperative kernel ----------
// 512 blocks x 256 threads (2 blocks/CU); block owns rows [blk*16,+16).
// One hidden barrier per layer: arrive -> GEMM-A (Hn + d@A, b-independent) -> wait;
// post-barrier GEMM-B ((b∘z)@A) with fused activation epilogue.
__global__ __launch_bounds__(THR, 2) void k_lamp(
    const float* __restrict__ u,
    const ushort_t* __restrict__ Afr, const ushort_t* __restrict__ Afi,
    const ushort_t* __restrict__ Atr, const ushort_t* __restrict__ Ati,
    const ushort_t* __restrict__ Dfr, const ushort_t* __restrict__ Dfi,
    const float* __restrict__ th,
    float* part, uint_t* cnt,
    float* __restrict__ out)
{
    extern __shared__ char dyn[];
    float*    pR   = (float*)dyn;                  // [2][3][16][17] 6528 B
    float*    pI   = pR + 2 * 3 * 16 * 17;         // 6528 B
    float*    zreL = pI + 2 * 3 * 16 * 17;         // 3328 B
    float*    zimL = zreL + RPB * ZS;              // 3328 B
    float*    redL = zimL + RPB * ZS;              // 128 B
    ushort_t* dbr  = (ushort_t*)(redL + 32);       // [16][64] 2048 B
    ushort_t* dbi  = dbr + 16 * 64;                // 2048 B
    ushort_t* zbr  = dbi + 16 * 64;                // 2048 B
    ushort_t* zbi  = zbr + 16 * 64;                // 2048 B
    ushort_t* HreL = zbi + 16 * 64;                // 16640 B
    ushort_t* HimL = HreL + RPB * HST;             // 16640 B => 61312 B

    const int tid = threadIdx.x, blk = blockIdx.x;
    const int row0 = blk * RPB;
    const int wave = tid >> 6, lane = tid & 63;
    const int quad = lane >> 4, m = lane & 15;
    const int kq = wave;                            // bwd/final: K-quarter
    const float2* u2 = (const float2*)u;
    uint_t tgt = NBLK;

    // prologue: u -> z LDS, zero K-pads of d/ẑ buffers, publish ||z0||^2, arrive
    {
        // zero pad cols 48..63 of the 4 bf16 staging buffers (written once)
        int r = tid >> 4, c = 48 + (tid & 15);
        dbr[r * 64 + c] = 0; dbi[r * 64 + c] = 0;
        zbr[r * 64 + c] = 0; zbi[r * 64 + c] = 0;
        float acc = 0.f;
        #pragma unroll
        for (int k3 = 0; k3 < 3; ++k3) {
            int j = tid + k3 * THR;
            int rr = j / 48, cc = j - rr * 48;
            float2 v = u2[(row0 + rr) * 48 + cc];
            zreL[rr * ZS + cc] = v.x; zimL[rr * ZS + cc] = v.y;
            acc += v.x * v.x + v.y * v.y;
        }
        float v[1] = {acc};
        reduce_vals<1>(v, redL, wave, lane);
        if (tid == 0) {
            astore(&part[blk * 8], redL[0] + redL[1] + redL[2] + redL[3]);
        }
        __syncthreads();
        if (tid == 0) bar_add(cnt, blk);
    }

    // layer-0 forward (hides init barrier)
    fwd_gemm0(Afr, Afi, zreL, zimL, HreL, HimL, wave, lane, quad, m);

    // init barrier -> sigma_0
    bar_wait(cnt, tgt);
    float lam, th1;
    {
        float v[1];
        v[0] = aload(&part[tid * 8]) + aload(&part[(tid + 256) * 8]);
        reduce_vals<1>(v, redL, wave, lane);
        float sig2 = redL[0] + redL[1] + redL[2] + redL[3];
        lam = th[0] * sqrtf(sig2 * (1.0f / 48.0f));
        th1 = th[1];
    }

    // layer-0 activation pass (R -> Hn), counts
    float cr = 0.f, ci = 0.f;
    {
        uint4* Hr4 = (uint4*)HreL;
        uint4* Hi4 = (uint4*)HimL;
        #pragma unroll
        for (int k4 = 0; k4 < 4; ++k4) {
            int j = tid + k4 * THR;
            int r = j >> 6, c4 = j & 63;
            uint4* pr = Hr4 + r * 65 + c4;
            uint4* pi = Hi4 + r * 65 + c4;
            uint4 xr = *pr, xi = *pi;
            xr.x = act2(xr.x, lam, th1, cr); xr.y = act2(xr.y, lam, th1, cr);
            xr.z = act2(xr.z, lam, th1, cr); xr.w = act2(xr.w, lam, th1, cr);
            xi.x = act2(xi.x, lam, th1, ci); xi.y = act2(xi.y, lam, th1, ci);
            xi.z = act2(xi.z, lam, th1, ci); xi.w = act2(xi.w, lam, th1, ci);
            *pr = xr; *pi = xi;
        }
        __syncthreads();
    }

    float dR[3], dI[3];
    for (int l = 0; l < L_ - 1; ++l) {
        // backward GEMM: h = Hn_l @ A_l; wave kq does K-quarter kq
        {
            const ushort_t* Atlr = Atr + (size_t)l * 24576;
            const ushort_t* Atli = Ati + (size_t)l * 24576;
            f32x4 aR[3], aI[3];
            #pragma unroll
            for (int q = 0; q < 3; ++q) { aR[q] = (f32x4){0,0,0,0}; aI[q] = (f32x4){0,0,0,0}; }
            #pragma unroll
            for (int ks = 0; ks < 4; ++ks) {
                const int ksa = kq * 4 + ks;
                const int k0 = ksa * 32 + quad * 8;
                short8 hr = *(const short8*)&HreL[m * HST + k0];
                short8 hi = *(const short8*)&HimL[m * HST + k0];
                short8 hin = negbf(hi);
                #pragma unroll
                for (int ft = 0; ft < 3; ++ft) {
                    short8 br = *(const short8*)(Atlr + (size_t)((ft * 16 + ksa) * 64 + lane) * 8);
                    short8 bi = *(const short8*)(Atli + (size_t)((ft * 16 + ksa) * 64 + lane) * 8);
                    aR[ft] = MFMA(hr, br, aR[ft]);
                    aR[ft] = MFMA(hin, bi, aR[ft]);
                    aI[ft] = MFMA(hr, bi, aI[ft]);
                    aI[ft] = MFMA(hi, br, aI[ft]);
                }
            }
            const int s = kq & 1;
            if (kq < 2) {
                #pragma unroll
                for (int ft = 0; ft < 3; ++ft)
                    #pragma unroll
                    for (int reg = 0; reg < 4; ++reg) {
                        pR[((s * 3 + ft) * 16 + quad * 4 + reg) * 17 + m] = aR[ft][reg];
                        pI[((s * 3 + ft) * 16 + quad * 4 + reg) * 17 + m] = aI[ft][reg];
                    }
            }
            __syncthreads();
            if (kq >= 2) {
                #pragma unroll
                for (int ft = 0; ft < 3; ++ft)
                    #pragma unroll
                    for (int reg = 0; reg < 4; ++reg) {
                        pR[((s * 3 + ft) * 16 + quad * 4 + reg) * 17 + m] += aR[ft][reg];
                        pI[((s * 3 + ft) * 16 + quad * 4 + reg) * 17 + m] += aI[ft][reg];
                    }
            }
            __syncthreads();
        }

        // S-pass: d = u - h (regs + bf16 staging), expansion sums
        float S1 = 0.f, S2r = 0.f, S2i = 0.f, S3r = 0.f, S3i = 0.f;
        #pragma unroll
        for (int k3 = 0; k3 < 3; ++k3) {
            int j = tid + k3 * THR;
            int r = j / 48, f = j - r * 48;
            int ft = f >> 4, c = f & 15;
            float hR = pR[(ft * 16 + r) * 17 + c] + pR[((3 + ft) * 16 + r) * 17 + c];
            float hI = pI[(ft * 16 + r) * 17 + c] + pI[((3 + ft) * 16 + r) * 17 + c];
            float2 uv = u2[(row0 + r) * 48 + f];
            float zr = zreL[r * ZS + f], zi = zimL[r * ZS + f];
            float dr = uv.x - hR, di = uv.y - hI;
            dR[k3] = dr; dI[k3] = di;
            dbr[r * 64 + f] = f2bf(dr);
            dbi[r * 64 + f] = f2bf(di);
            S1  += dr * dr + di * di;
            S2r += dr * zr; S2i += di * zi;
            S3r += zr * zr; S3i += zi * zi;
        }
        // publish {cr, ci, S1, S2r, S2i, S3r, S3i}; arrive
        {
            float v[7] = {cr, ci, S1, S2r, S2i, S3r, S3i};
            reduce_vals<7>(v, redL, wave, lane);
            if (tid < 7) {
                float t0 = redL[tid * NW] + redL[tid * NW + 1] + redL[tid * NW + 2] + redL[tid * NW + 3];
                astore(&part[blk * 8 + tid], t0);
            }
            __syncthreads();
            if (tid == 0) bar_add(cnt, blk);
            tgt += NBLK;
        }

        // GEMM-A (hides barrier): R_partial = Hn_l + d@A_{l+1}
        {
            const ushort_t* Aflr = Afr + (size_t)(l + 1) * 32768;
            const ushort_t* Afli = Afi + (size_t)(l + 1) * 32768;
            short8 dr0 = *(const short8*)&dbr[m * 64 + quad * 8];
            short8 dr1 = *(const short8*)&dbr[m * 64 + 32 + quad * 8];
            short8 di0 = *(const short8*)&dbi[m * 64 + quad * 8];
            short8 di1 = *(const short8*)&dbi[m * 64 + 32 + quad * 8];
            short8 din0 = negbf(di0), din1 = negbf(di1);
            #pragma unroll
            for (int ct = 0; ct < 8; ++ct) {
                const int tile = wave * 8 + ct;
                const ushort_t* rp = Aflr + (size_t)(tile * 2) * 512 + lane * 8;
                const ushort_t* ip = Afli + (size_t)(tile * 2) * 512 + lane * 8;
                short8 ar0 = *(const short8*)rp;
                short8 ar1 = *(const short8*)(rp + 512);
                short8 ai0 = *(const short8*)ip;
                short8 ai1 = *(const short8*)(ip + 512);
                f32x4 accR = {0.f,0.f,0.f,0.f}, accI = {0.f,0.f,0.f,0.f};
                accR = MFMA(dr0, ar0, accR);
                accR = MFMA(dr1, ar1, accR);
                accR = MFMA(din0, ai0, accR);
                accR = MFMA(din1, ai1, accR);
                accI = MFMA(dr0, ai0, accI);
                accI = MFMA(dr1, ai1, accI);
                accI = MFMA(di0, ar0, accI);
                accI = MFMA(di1, ar1, accI);
                const int t = tile * 16 + m;
                #pragma unroll
                for (int reg = 0; reg < 4; ++reg) {
                    const int lr = quad * 4 + reg;
                    HreL[lr * HST + t] = f2bf(bf2f(HreL[lr * HST + t]) + accR[reg]);
                    HimL[lr * HST + t] = f2bf(bf2f(HimL[lr * HST + t]) + accI[reg]);
                }
            }
        }

        // barrier -> b_l, sigma_{l+1}, lambda_{l+1}
        bar_wait(cnt, tgt);
        float bre, bim;
        {
            float v[7];
            #pragma unroll
            for (int q = 0; q < 7; ++q)
                v[q] = aload(&part[tid * 8 + q]) + aload(&part[(tid + 256) * 8 + q]);
            reduce_vals<7>(v, redL, wave, lane);
            float tot[7];
            #pragma unroll
            for (int q = 0; q < 7; ++q)
                tot[q] = redL[q * NW] + redL[q * NW + 1] + redL[q * NW + 2] + redL[q * NW + 3];
            bre = th1 * tot[0] * (1.0f / 48.0f);
            bim = th1 * tot[1] * (1.0f / 48.0f);
            float sig2 = tot[2] + 2.f * bre * tot[3] + 2.f * bim * tot[4]
                       + bre * bre * tot[5] + bim * bim * tot[6];
            lam = th[(l + 1) * 3] * sqrtf(sig2 * (1.0f / 48.0f));
            th1 = th[(l + 1) * 3 + 1];
        }

        // scale pass: ẑ = b∘z (bf16 staging), z_{l+1} = d + b∘z (fp32 master)
        #pragma unroll
        for (int k3 = 0; k3 < 3; ++k3) {
            int j = tid + k3 * THR;
            int r = j / 48, f = j - r * 48;
            float zr = zreL[r * ZS + f], zi = zimL[r * ZS + f];
            float zhr = bre * zr, zhi = bim * zi;
            zbr[r * 64 + f] = f2bf(zhr);
            zbi[r * 64 + f] = f2bf(zhi);
            zreL[r * ZS + f] = dR[k3] + zhr;
            zimL[r * ZS + f] = dI[k3] + zhi;
        }
        __syncthreads();

        // GEMM-B: R = R_partial + ẑ@A_{l+1}, fused activation -> Hn_{l+1}, counts
        cr = 0.f; ci = 0.f;
        {
            const ushort_t* Aflr = Afr + (size_t)(l + 1) * 32768;
            const ushort_t* Afli = Afi + (size_t)(l + 1) * 32768;
            short8 zr0 = *(const short8*)&zbr[m * 64 + quad * 8];
            short8 zr1 = *(const short8*)&zbr[m * 64 + 32 + quad * 8];
            short8 zi0 = *(const short8*)&zbi[m * 64 + quad * 8];
            short8 zi1 = *(const short8*)&zbi[m * 64 + 32 + quad * 8];
            short8 zin0 = negbf(zi0), zin1 = negbf(zi1);
            #pragma unroll
            for (int ct = 0; ct < 8; ++ct) {
                const int tile = wave * 8 + ct;
                const ushort_t* rp = Aflr + (size_t)(tile * 2) * 512 + lane * 8;
                const ushort_t* ip = Afli + (size_t)(tile * 2) * 512 + lane * 8;
                short8 ar0 = *(const short8*)rp;
                short8 ar1 = *(const short8*)(rp + 512);
                short8 ai0 = *(const short8*)ip;
                short8 ai1 = *(const short8*)(ip + 512);
                f32x4 accR = {0.f,0.f,0.f,0.f}, accI = {0.f,0.f,0.f,0.f};
                accR = MFMA(zr0, ar0, accR);
                accR = MFMA(zr1, ar1, accR);
                accR = MFMA(zin0, ai0, accR);
                accR = MFMA(zin1, ai1, accR);
                accI = MFMA(zr0, ai0, accI);
                accI = MFMA(zr1, ai1, accI);
                accI = MFMA(zi0, ar0, accI);
                accI = MFMA(zi1, ar1, accI);
                const int t = tile * 16 + m;
                #pragma unroll
                for (int reg = 0; reg < 4; ++reg) {
                    const int lr = quad * 4 + reg;
                    float Rr = bf2f(HreL[lr * HST + t]) + accR[reg];
                    float Ri = bf2f(HimL[lr * HST + t]) + accI[reg];
                    float mr = fabsf(Rr), mi = fabsf(Ri);
                    float fr = th1 * copysignf(fmaxf(mr - lam, 0.f), Rr);
                    float fi = th1 * copysignf(fmaxf(mi - lam, 0.f), Ri);
                    cr += (mr > lam) ? 1.f : 0.f;
                    ci += (mi > lam) ? 1.f : 0.f;
                    HreL[lr * HST + t] = f2bf(fr);
                    HimL[lr * HST + t] = f2bf(fi);
                }
            }
            __syncthreads();
        }
    }

    // final: out = Hn_7(LDS) @ DFT (wave kq, 4-way K, two-phase combine)
    {
        f32x4 fR[3], fI[3];
        #pragma unroll
        for (int q = 0; q < 3; ++q) { fR[q] = (f32x4){0,0,0,0}; fI[q] = (f32x4){0,0,0,0}; }
        #pragma unroll
        for (int ks = 0; ks < 4; ++ks) {
            const int ksa = kq * 4 + ks;
            const int k0 = ksa * 32 + quad * 8;
            short8 hr = *(const short8*)&HreL[m * HST + k0];
            short8 hi = *(const short8*)&HimL[m * HST + k0];
            short8 hin = negbf(hi);
            #pragma unroll
            for (int ft = 0; ft < 3; ++ft) {
                short8 br = *(const short8*)(Dfr + (size_t)((ft * 16 + ksa) * 64 + lane) * 8);
                short8 bi = *(const short8*)(Dfi + (size_t)((ft * 16 + ksa) * 64 + lane) * 8);
                fR[ft] = MFMA(hr, br, fR[ft]);
                fR[ft] = MFMA(hin, bi, fR[ft]);
                fI[ft] = MFMA(hr, bi, fI[ft]);
                fI[ft] = MFMA(hi, br, fI[ft]);
            }
        }
        const int s = kq & 1;
        if (kq < 2) {
            #pragma unroll
            for (int ft = 0; ft < 3; ++ft)
                #pragma unroll
                for (int reg = 0; reg < 4; ++reg) {
                    pR[((s * 3 + ft) * 16 + quad * 4 + reg) * 17 + m] = fR[ft][reg];
                    pI[((s * 3 + ft) * 16 + quad * 4 + reg) * 17 + m] = fI[ft][reg];
                }
        }
        __syncthreads();
        if (kq >= 2) {
            #pragma unroll
            for (int ft = 0; ft < 3; ++ft)
                #pragma unroll
                for (int reg = 0; reg < 4; ++reg) {
                    pR[((s * 3 + ft) * 16 + quad * 4 + reg) * 17 + m] += fR[ft][reg];
                    pI[((s * 3 + ft) * 16 + quad * 4 + reg) * 17 + m] += fI[ft][reg];
                }
        }
        __syncthreads();
        float2* out2 = (float2*)out;
        #pragma unroll
        for (int k3 = 0; k3 < 3; ++k3) {
            int j = tid + k3 * THR;
            int r = j / 48, f = j - r * 48;
            int ft = f >> 4, c = f & 15;
            float hR = pR[(ft * 16 + r) * 17 + c] + pR[((3 + ft) * 16 + r) * 17 + c];
            float hI = pI[(ft * 16 + r) * 17 + c] + pI[((3 + ft) * 16 + r) * 17 + c];
            out2[(row0 + r) * 48 + f] = make_float2(hR, hI);
        }
    }
}

extern "C" void kernel_launch(void* const* d_in, const int* in_sizes, int n_in,
                              void* d_out, int out_size, void* d_ws, size_t ws_size,
                              hipStream_t stream) {
    (void)in_sizes; (void)n_in; (void)out_size; (void)ws_size;
    const float* u  = (const float*)d_in[0];
    const float* Ar = (const float*)d_in[1];
    const float* Ai = (const float*)d_in[2];
    const float* th = (const float*)d_in[3];
    const float* Dr = (const float*)d_in[4];
    const float* Di = (const float*)d_in[5];
    float* out = (float*)d_out;

    char* p = (char*)d_ws;
    auto alloc = [&](size_t bytes) -> char* {
        char* r = p;
        p += (bytes + 255) & ~(size_t)255;
        return r;
    };
    float*    part = (float*)alloc((size_t)NBLK * 8 * 4);   // [512][8]
    uint_t*   cnt  = (uint_t*)alloc(512 * 4);               // 16 shards on 128B lines
    ushort_t* Afr = (ushort_t*)alloc((size_t)L_ * 32768 * 2);
    ushort_t* Afi = (ushort_t*)alloc((size_t)L_ * 32768 * 2);
    ushort_t* Atr = (ushort_t*)alloc((size_t)L_ * 24576 * 2);
    ushort_t* Ati = (ushort_t*)alloc((size_t)L_ * 24576 * 2);
    ushort_t* Dfr = (ushort_t*)alloc((size_t)24576 * 2);
    ushort_t* Dfi = (ushort_t*)alloc((size_t)24576 * 2);

    k_pre<<<256, 256, 0, stream>>>(Ar, Ai, Dr, Di, Afr, Afi, Atr, Ati, Dfr, Dfi, cnt);

    const uint_t lds_bytes = 61312;
    hipFuncSetAttribute((const void*)k_lamp,
                        hipFuncAttributeMaxDynamicSharedMemorySize, (int)lds_bytes);
    void* args[] = { (void*)&u, (void*)&Afr, (void*)&Afi, (void*)&Atr, (void*)&Ati,
                     (void*)&Dfr, (void*)&Dfi, (void*)&th,
                     (void*)&part, (void*)&cnt, (void*)&out };
    hipLaunchCooperativeKernel((void*)k_lamp, dim3(NBLK), dim3(THR), args,
                               lds_bytes, stream);
}